// Round 7
// baseline (366.523 us; speedup 1.0000x reference)
//
#include <hip/hip_runtime.h>
#include <stdint.h>

typedef __bf16 bf16x8 __attribute__((ext_vector_type(8)));
typedef float  f32x4  __attribute__((ext_vector_type(4)));
typedef uint32_t u32x4 __attribute__((ext_vector_type(4)));

__device__ __forceinline__ uint16_t f2bf(float f) {
    uint32_t u = __builtin_bit_cast(uint32_t, f);
    u += 0x7FFFu + ((u >> 16) & 1u);          // round-to-nearest-even
    return (uint16_t)(u >> 16);
}

// ---------------------------------------------------------------------------
// Kernel 1: Q [b][c 256][i 32][j 32] f32 -> Qt [b][ih 2][j 32][ch 32][il 16][8] bf16
//   (c = ch*8 + t, i = ih*16 + il).  Also zeroes the P accumulator buffer.
// ---------------------------------------------------------------------------
__global__ __launch_bounds__(256) void qtrans_kernel(const float* __restrict__ Q,
                                                     uint16_t* __restrict__ Qt,
                                                     float* __restrict__ P) {
    // T[c8 8][i 32][j 33] f32, c8-stride 1064 so bank = 8*c8 + i + j
    __shared__ float T[8 * 1064];
    const int ch = blockIdx.x, b = blockIdx.y;
    const int tid = threadIdx.x;

    {   // zero P[16*64*32*80] = 2,621,440 f32 across 512 blocks (f32x4 stores)
        const f32x4 z = {};
        f32x4* P4 = (f32x4*)P;
        size_t base = (size_t)(b * 32 + ch) * 1280 + tid;
        #pragma unroll
        for (int k = 0; k < 5; ++k) P4[base + k * 256] = z;
    }

    const float* src = Q + ((size_t)(b * 256 + ch * 8)) * 1024;
    #pragma unroll
    for (int it = 0; it < 8; ++it) {                   // 2048 f32x4, coalesced
        int idx4 = tid + it * 256;
        int c8 = idx4 >> 8, rem4 = idx4 & 255;
        f32x4 v = *(const f32x4*)(src + (size_t)c8 * 1024 + rem4 * 4);
        int i = (rem4 * 4) >> 5, j = (rem4 * 4) & 31;
        float* tr = &T[c8 * 1064 + i * 33 + j];
        tr[0] = v[0]; tr[1] = v[1]; tr[2] = v[2]; tr[3] = v[3];
    }
    __syncthreads();

    uint32_t* dst = (uint32_t*)Qt;                     // write bf16 pairs
    #pragma unroll
    for (int it = 0; it < 16; ++it) {                  // 4096 pairs
        int o2 = tid + it * 256;
        int t  = (o2 & 3) * 2;
        int il = (o2 >> 2) & 15;
        int j  = (o2 >> 6) & 31;
        int ih = (o2 >> 11) & 1;
        float v0 = T[t * 1064 + (ih * 16 + il) * 33 + j];
        float v1 = T[(t + 1) * 1064 + (ih * 16 + il) * 33 + j];
        uint32_t pk = (uint32_t)f2bf(v0) | ((uint32_t)f2bf(v1) << 16);
        size_t oi = ((((size_t)(b * 2 + ih) * 32 + j) * 32 + ch) * 16 + il) * 4 + (t >> 1);
        dst[oi] = pk;
    }
}

// ---------------------------------------------------------------------------
// Kernel 2: block = (d, half, b) — R3's proven core over HALF the channels.
//   LDS S_l[ch 16][row 80] 16B chunks = 20 KB -> 8 blocks/CU, 32 waves/CU.
//   row = sx+16; rows 0..15 zero, OOB clamped to zero-row 0. Conflict-free
//   b128 A-reads. Wave w owns j0a = w+4jj (0..15), j0b = j0a+16; A fragment
//   t serves (m=t, j0a) and (m=t-1, j0b): 5 A-reads / 18 MFMA per s-iter.
//   K-split (half) partials atomicAdd into P[b][d][iv][x] (<=2 writers/word).
// ---------------------------------------------------------------------------
__global__ __launch_bounds__(256, 8) void corr_kernel(const float* __restrict__ S,
                                                      const uint16_t* __restrict__ Qt,
                                                      float* __restrict__ P) {
    __shared__ __align__(16) char smem[20480];         // 20 KB -> 8 blocks/CU
    uint16_t* S_l = (uint16_t*)smem;                   // [ch16][row80]: ch*640+row*8 (u16)
    float*    Pw  = (float*)smem;                      // overlay: [2][iv 32][x 80] f32

    const int d    = blockIdx.x;                       // 0..63
    const int half = blockIdx.y;                       // 0..1 (c-range half)
    const int b    = blockIdx.z;                       // 0..15
    const int tid = threadIdx.x, wave = tid >> 6, lane = tid & 63;
    const int l15 = lane & 15, l4 = lane >> 4;

    // ---- zero-fill pad rows 0..15 (all 16 ch): 4 KB
    {
        const u32x4 z = {};
        if (tid < 256) {
            int zi = tid;                              // 16 ch x 16 rows
            int ch = zi >> 4, r = zi & 15;
            *(u32x4*)&S_l[ch * 640 + r * 8] = z;
        }
    }
    // ---- stage S[b, half*128 + 0..127, d, :] -> S_l[chl][sx+16]
    {
        const int sx = tid & 63, w = tid >> 6;
        const float* sp = S + ((size_t)(b * 256 + half * 128)) * 4096 + (size_t)d * 64;
        #pragma unroll
        for (int k = 0; k < 4; ++k) {
            int chl = w * 4 + k;                       // 0..15
            float v[8];
            #pragma unroll
            for (int cc = 0; cc < 8; ++cc)
                v[cc] = sp[(size_t)(chl * 8 + cc) * 4096 + sx];  // 256B coalesced
            u32x4 pk;
            #pragma unroll
            for (int q = 0; q < 4; ++q)
                pk[q] = (uint32_t)f2bf(v[2 * q]) | ((uint32_t)f2bf(v[2 * q + 1]) << 16);
            *(u32x4*)&S_l[chl * 640 + (sx + 16) * 8] = pk;       // contiguous 1KB/wave
        }
    }
    __syncthreads();

    f32x4 acc[5][2] = {};

    #pragma unroll
    for (int jj = 0; jj < 4; ++jj) {
        const int j0a = wave + jj * 4;                 // 0..15 ; j0b = j0a+16
        const uint16_t* qa0 = Qt + (((size_t)b * 2 + 0) * 32 + j0a) * 4096
                                 + (half * 16 + l4) * 128 + l15 * 8;
        const uint16_t* qa1 = Qt + (((size_t)b * 2 + 1) * 32 + j0a) * 4096
                                 + (half * 16 + l4) * 128 + l15 * 8;
        const uint16_t* qb0 = qa0 + 16 * 4096;
        const uint16_t* qb1 = qa1 + 16 * 4096;

        int rowt[5];
        #pragma unroll
        for (int t = 0; t < 5; ++t) {
            int rr = j0a + t * 16 + l15;               // <= 94
            rowt[t] = (rr < 80) ? rr : 0;              // OOB -> zero-row (x>=65 garbage)
        }

        #pragma unroll
        for (int s = 0; s < 4; ++s) {                  // 16 ch-chunks in this half
            bf16x8 Ba0 = *(const bf16x8*)(qa0 + s * 512);
            bf16x8 Ba1 = *(const bf16x8*)(qa1 + s * 512);
            bf16x8 Bb0 = *(const bf16x8*)(qb0 + s * 512);
            bf16x8 Bb1 = *(const bf16x8*)(qb1 + s * 512);
            const int chb = (s * 4 + l4) * 640;
            bf16x8 A[5];
            #pragma unroll
            for (int t = 0; t < 5; ++t)
                A[t] = *(const bf16x8*)&S_l[chb + rowt[t] * 8];  // conflict-free b128
            #pragma unroll
            for (int t = 0; t < 5; ++t) {
                acc[t][0] = __builtin_amdgcn_mfma_f32_16x16x32_bf16(A[t], Ba0, acc[t][0], 0, 0, 0);
                acc[t][1] = __builtin_amdgcn_mfma_f32_16x16x32_bf16(A[t], Ba1, acc[t][1], 0, 0, 0);
            }
            #pragma unroll
            for (int t = 1; t < 5; ++t) {
                acc[t - 1][0] = __builtin_amdgcn_mfma_f32_16x16x32_bf16(A[t], Bb0, acc[t - 1][0], 0, 0, 0);
                acc[t - 1][1] = __builtin_amdgcn_mfma_f32_16x16x32_bf16(A[t], Bb1, acc[t - 1][1], 0, 0, 0);
            }
        }
    }

    // ---- 2-round merge (20 KB holds 2 planes), then atomicAdd into P
    __syncthreads();                                   // all S_l reads done
    if (wave < 2) {
        float* pw = Pw + wave * 2560;                  // plane = wave
        #pragma unroll
        for (int m = 0; m < 5; ++m)
            #pragma unroll
            for (int n = 0; n < 2; ++n)
                *(f32x4*)&pw[(n * 16 + l15) * 80 + m * 16 + l4 * 4] = acc[m][n];
    }
    __syncthreads();
    if (wave >= 2) {                                   // rmw same elements, disjoint
        float* pw = Pw + (wave - 2) * 2560;
        #pragma unroll
        for (int m = 0; m < 5; ++m)
            #pragma unroll
            for (int n = 0; n < 2; ++n) {
                float* p = &pw[(n * 16 + l15) * 80 + m * 16 + l4 * 4];
                f32x4 t = *(f32x4*)p;
                t += acc[m][n];
                *(f32x4*)p = t;
            }
    }
    __syncthreads();
    float* Pd = P + (size_t)(b * 64 + d) * 2560;       // P[b][d][iv*80+x]
    for (int e = tid; e < 2560; e += 256) {
        float v = Pw[e] + Pw[2560 + e];
        atomicAdd(Pd + e, v);                          // 2 writers (half=0,1)
    }
}

// ---------------------------------------------------------------------------
// Kernel 3: out[b,y,x] = sum_i P[b][d=y+i-16][i][x]
// ---------------------------------------------------------------------------
__global__ __launch_bounds__(128) void reduce_kernel(const float* __restrict__ P,
                                                     float* __restrict__ out) {
    const int y = blockIdx.x, b = blockIdx.y;
    const int x = threadIdx.x;
    if (x >= 65) return;
    int ilo = 16 - y; if (ilo < 0) ilo = 0;
    int ihi = 80 - y; if (ihi > 32) ihi = 32;
    float s = 0.f;
    const float* Pb = P + (size_t)b * (64 * 2560) + x;
    for (int i = ilo; i < ihi; ++i)
        s += Pb[(size_t)(y + i - 16) * 2560 + i * 80];
    out[(size_t)b * 4225 + (size_t)y * 65 + x] = s;
}

// ---------------------------------------------------------------------------
// fp32 fallback (only if workspace is too small) — slow but exact
// ---------------------------------------------------------------------------
__global__ __launch_bounds__(256) void naive_kernel(const float* __restrict__ Q,
                                                    const float* __restrict__ S,
                                                    float* __restrict__ out) {
    int gid = blockIdx.x * 256 + threadIdx.x;
    if (gid >= 67600) return;
    int b = gid / 4225, r = gid % 4225, y = r / 65, x = r % 65;
    int jlo = 16 - x; if (jlo < 0) jlo = 0;
    int jhi = 80 - x; if (jhi > 32) jhi = 32;
    float acc = 0.f;
    for (int c = 0; c < 256; ++c) {
        const float* Sb = S + ((size_t)(b * 256 + c)) * 4096;
        const float* Qb = Q + ((size_t)(b * 256 + c)) * 1024;
        for (int i = 0; i < 32; ++i) {
            int dd = y + i - 16;
            if ((unsigned)dd >= 64u) continue;
            const float* Sr = Sb + dd * 64 + (x - 16);
            const float* Qr = Qb + i * 32;
            for (int j = jlo; j < jhi; ++j) acc += Sr[j] * Qr[j];
        }
    }
    out[gid] = acc;
}

extern "C" void kernel_launch(void* const* d_in, const int* in_sizes, int n_in,
                              void* d_out, int out_size, void* d_ws, size_t ws_size,
                              hipStream_t stream) {
    (void)in_sizes; (void)n_in; (void)out_size;
    const float* Q = (const float*)d_in[0];   // [16,256,32,32] f32
    const float* S = (const float*)d_in[1];   // [16,256,64,64] f32
    float* out = (float*)d_out;               // [16,1,65,65] f32

    const size_t QT_BYTES = (size_t)16 * 2 * 32 * 32 * 16 * 8 * 2;  //  8,388,608
    const size_t P_BYTES  = (size_t)16 * 64 * 32 * 80 * 4;          // 10,485,760

    if (ws_size < QT_BYTES + P_BYTES) {       // == 18,874,368, proven available
        naive_kernel<<<(67600 + 255) / 256, 256, 0, stream>>>(Q, S, out);
        return;
    }
    uint16_t* Qt = (uint16_t*)d_ws;
    float*    P  = (float*)((char*)d_ws + QT_BYTES);

    qtrans_kernel<<<dim3(32, 16), 256, 0, stream>>>(Q, Qt, P);
    corr_kernel<<<dim3(64, 2, 16), 256, 0, stream>>>(S, Qt, P);
    reduce_kernel<<<dim3(65, 16), 128, 0, stream>>>(P, out);
}

// Round 8
// 145.328 us; speedup vs baseline: 2.5220x; 2.5220x over previous
//
#include <hip/hip_runtime.h>
#include <stdint.h>

typedef __bf16 bf16x8 __attribute__((ext_vector_type(8)));
typedef float  f32x4  __attribute__((ext_vector_type(4)));
typedef uint32_t u32x4 __attribute__((ext_vector_type(4)));

__device__ __forceinline__ uint16_t f2bf(float f) {
    uint32_t u = __builtin_bit_cast(uint32_t, f);
    u += 0x7FFFu + ((u >> 16) & 1u);          // round-to-nearest-even
    return (uint16_t)(u >> 16);
}

// ---------------------------------------------------------------------------
// Kernel 1: Q [b][c 256][i 32][j 32] f32 -> Qt [b][ih 2][j 32][ch 32][il 16][8] bf16
//   (c = ch*8 + t, i = ih*16 + il).  Also zeroes the P accumulator buffer.
// ---------------------------------------------------------------------------
__global__ __launch_bounds__(256) void qtrans_kernel(const float* __restrict__ Q,
                                                     uint16_t* __restrict__ Qt,
                                                     float* __restrict__ P) {
    // T[c8 8][i 32][j 33] f32, c8-stride 1064 so bank = 8*c8 + i + j
    __shared__ float T[8 * 1064];
    const int ch = blockIdx.x, b = blockIdx.y;
    const int tid = threadIdx.x;

    {   // zero P[16*64*32*80] = 2,621,440 f32 across 512 blocks (f32x4 stores)
        const f32x4 z = {};
        f32x4* P4 = (f32x4*)P;
        size_t base = (size_t)(b * 32 + ch) * 1280 + tid;
        #pragma unroll
        for (int k = 0; k < 5; ++k) P4[base + k * 256] = z;
    }

    const float* src = Q + ((size_t)(b * 256 + ch * 8)) * 1024;
    #pragma unroll
    for (int it = 0; it < 8; ++it) {                   // 2048 f32x4, coalesced
        int idx4 = tid + it * 256;
        int c8 = idx4 >> 8, rem4 = idx4 & 255;
        f32x4 v = *(const f32x4*)(src + (size_t)c8 * 1024 + rem4 * 4);
        int i = (rem4 * 4) >> 5, j = (rem4 * 4) & 31;
        float* tr = &T[c8 * 1064 + i * 33 + j];
        tr[0] = v[0]; tr[1] = v[1]; tr[2] = v[2]; tr[3] = v[3];
    }
    __syncthreads();

    uint32_t* dst = (uint32_t*)Qt;                     // write bf16 pairs
    #pragma unroll
    for (int it = 0; it < 16; ++it) {                  // 4096 pairs
        int o2 = tid + it * 256;
        int t  = (o2 & 3) * 2;
        int il = (o2 >> 2) & 15;
        int j  = (o2 >> 6) & 31;
        int ih = (o2 >> 11) & 1;
        float v0 = T[t * 1064 + (ih * 16 + il) * 33 + j];
        float v1 = T[(t + 1) * 1064 + (ih * 16 + il) * 33 + j];
        uint32_t pk = (uint32_t)f2bf(v0) | ((uint32_t)f2bf(v1) << 16);
        size_t oi = ((((size_t)(b * 2 + ih) * 32 + j) * 32 + ch) * 16 + il) * 4 + (t >> 1);
        dst[oi] = pk;
    }
}

// ---------------------------------------------------------------------------
// Kernel 2: block = (d, half, b) — R3's proven core over HALF the channels.
//   LDS S_l[ch 16][row 80] 16B chunks = 20 KB; with 64 VGPR the HW can run
//   8 blocks/CU = 32 waves/CU (double R3).  __launch_bounds__(256,4) matches
//   R3's proven 64-VGPR allocation — (256,8) clamped to 32 VGPR and spilled.
//   row = sx+16; rows 0..15 zero, OOB clamped to zero-row 0. Conflict-free
//   b128 A-reads. Wave w owns j0a = w+4jj (0..15), j0b = j0a+16; A fragment
//   t serves (m=t, j0a) and (m=t-1, j0b): 5 A-reads / 18 MFMA per s-iter.
//   K-split (half) partials atomicAdd into P[b][d][iv][x] (<=2 writers/word).
// ---------------------------------------------------------------------------
__global__ __launch_bounds__(256, 4) void corr_kernel(const float* __restrict__ S,
                                                      const uint16_t* __restrict__ Qt,
                                                      float* __restrict__ P) {
    __shared__ __align__(16) char smem[20480];         // 20 KB -> LDS allows 8 blocks/CU
    uint16_t* S_l = (uint16_t*)smem;                   // [ch16][row80]: ch*640+row*8 (u16)
    float*    Pw  = (float*)smem;                      // overlay: [2][iv 32][x 80] f32

    const int d    = blockIdx.x;                       // 0..63
    const int half = blockIdx.y;                       // 0..1 (c-range half)
    const int b    = blockIdx.z;                       // 0..15
    const int tid = threadIdx.x, wave = tid >> 6, lane = tid & 63;
    const int l15 = lane & 15, l4 = lane >> 4;

    // ---- zero-fill pad rows 0..15 (all 16 ch): 4 KB
    {
        const u32x4 z = {};
        int ch = tid >> 4, r = tid & 15;               // 256 threads = 16ch x 16rows
        *(u32x4*)&S_l[ch * 640 + r * 8] = z;
    }
    // ---- stage S[b, half*128 + 0..127, d, :] -> S_l[chl][sx+16]
    {
        const int sx = tid & 63, w = tid >> 6;
        const float* sp = S + ((size_t)(b * 256 + half * 128)) * 4096 + (size_t)d * 64;
        #pragma unroll
        for (int k = 0; k < 4; ++k) {
            int chl = w * 4 + k;                       // 0..15
            float v[8];
            #pragma unroll
            for (int cc = 0; cc < 8; ++cc)
                v[cc] = sp[(size_t)(chl * 8 + cc) * 4096 + sx];  // 256B coalesced
            u32x4 pk;
            #pragma unroll
            for (int q = 0; q < 4; ++q)
                pk[q] = (uint32_t)f2bf(v[2 * q]) | ((uint32_t)f2bf(v[2 * q + 1]) << 16);
            *(u32x4*)&S_l[chl * 640 + (sx + 16) * 8] = pk;       // contiguous 1KB/wave
        }
    }
    __syncthreads();

    f32x4 acc[5][2] = {};

    #pragma unroll
    for (int jj = 0; jj < 4; ++jj) {
        const int j0a = wave + jj * 4;                 // 0..15 ; j0b = j0a+16
        const uint16_t* qa0 = Qt + (((size_t)b * 2 + 0) * 32 + j0a) * 4096
                                 + (half * 16 + l4) * 128 + l15 * 8;
        const uint16_t* qa1 = Qt + (((size_t)b * 2 + 1) * 32 + j0a) * 4096
                                 + (half * 16 + l4) * 128 + l15 * 8;
        const uint16_t* qb0 = qa0 + 16 * 4096;
        const uint16_t* qb1 = qa1 + 16 * 4096;

        int rowt[5];
        #pragma unroll
        for (int t = 0; t < 5; ++t) {
            int rr = j0a + t * 16 + l15;               // <= 94
            rowt[t] = (rr < 80) ? rr : 0;              // OOB -> zero-row (x>=65 garbage)
        }

        #pragma unroll
        for (int s = 0; s < 4; ++s) {                  // 16 ch-chunks in this half
            bf16x8 Ba0 = *(const bf16x8*)(qa0 + s * 512);
            bf16x8 Ba1 = *(const bf16x8*)(qa1 + s * 512);
            bf16x8 Bb0 = *(const bf16x8*)(qb0 + s * 512);
            bf16x8 Bb1 = *(const bf16x8*)(qb1 + s * 512);
            const int chb = (s * 4 + l4) * 640;
            bf16x8 A[5];
            #pragma unroll
            for (int t = 0; t < 5; ++t)
                A[t] = *(const bf16x8*)&S_l[chb + rowt[t] * 8];  // conflict-free b128
            #pragma unroll
            for (int t = 0; t < 5; ++t) {
                acc[t][0] = __builtin_amdgcn_mfma_f32_16x16x32_bf16(A[t], Ba0, acc[t][0], 0, 0, 0);
                acc[t][1] = __builtin_amdgcn_mfma_f32_16x16x32_bf16(A[t], Ba1, acc[t][1], 0, 0, 0);
            }
            #pragma unroll
            for (int t = 1; t < 5; ++t) {
                acc[t - 1][0] = __builtin_amdgcn_mfma_f32_16x16x32_bf16(A[t], Bb0, acc[t - 1][0], 0, 0, 0);
                acc[t - 1][1] = __builtin_amdgcn_mfma_f32_16x16x32_bf16(A[t], Bb1, acc[t - 1][1], 0, 0, 0);
            }
        }
    }

    // ---- 2-round merge (20 KB holds 2 planes), then atomicAdd into P
    __syncthreads();                                   // all S_l reads done
    if (wave < 2) {
        float* pw = Pw + wave * 2560;                  // plane = wave
        #pragma unroll
        for (int m = 0; m < 5; ++m)
            #pragma unroll
            for (int n = 0; n < 2; ++n)
                *(f32x4*)&pw[(n * 16 + l15) * 80 + m * 16 + l4 * 4] = acc[m][n];
    }
    __syncthreads();
    if (wave >= 2) {                                   // rmw same elements, disjoint
        float* pw = Pw + (wave - 2) * 2560;
        #pragma unroll
        for (int m = 0; m < 5; ++m)
            #pragma unroll
            for (int n = 0; n < 2; ++n) {
                float* p = &pw[(n * 16 + l15) * 80 + m * 16 + l4 * 4];
                f32x4 t = *(f32x4*)p;
                t += acc[m][n];
                *(f32x4*)p = t;
            }
    }
    __syncthreads();
    float* Pd = P + (size_t)(b * 64 + d) * 2560;       // P[b][d][iv*80+x]
    for (int e = tid; e < 2560; e += 256) {
        float v = Pw[e] + Pw[2560 + e];
        atomicAdd(Pd + e, v);                          // 2 writers (half=0,1)
    }
}

// ---------------------------------------------------------------------------
// Kernel 3: out[b,y,x] = sum_i P[b][d=y+i-16][i][x]
// ---------------------------------------------------------------------------
__global__ __launch_bounds__(128) void reduce_kernel(const float* __restrict__ P,
                                                     float* __restrict__ out) {
    const int y = blockIdx.x, b = blockIdx.y;
    const int x = threadIdx.x;
    if (x >= 65) return;
    int ilo = 16 - y; if (ilo < 0) ilo = 0;
    int ihi = 80 - y; if (ihi > 32) ihi = 32;
    float s = 0.f;
    const float* Pb = P + (size_t)b * (64 * 2560) + x;
    for (int i = ilo; i < ihi; ++i)
        s += Pb[(size_t)(y + i - 16) * 2560 + i * 80];
    out[(size_t)b * 4225 + (size_t)y * 65 + x] = s;
}

// ---------------------------------------------------------------------------
// fp32 fallback (only if workspace is too small) — slow but exact
// ---------------------------------------------------------------------------
__global__ __launch_bounds__(256) void naive_kernel(const float* __restrict__ Q,
                                                    const float* __restrict__ S,
                                                    float* __restrict__ out) {
    int gid = blockIdx.x * 256 + threadIdx.x;
    if (gid >= 67600) return;
    int b = gid / 4225, r = gid % 4225, y = r / 65, x = r % 65;
    int jlo = 16 - x; if (jlo < 0) jlo = 0;
    int jhi = 80 - x; if (jhi > 32) jhi = 32;
    float acc = 0.f;
    for (int c = 0; c < 256; ++c) {
        const float* Sb = S + ((size_t)(b * 256 + c)) * 4096;
        const float* Qb = Q + ((size_t)(b * 256 + c)) * 1024;
        for (int i = 0; i < 32; ++i) {
            int dd = y + i - 16;
            if ((unsigned)dd >= 64u) continue;
            const float* Sr = Sb + dd * 64 + (x - 16);
            const float* Qr = Qb + i * 32;
            for (int j = jlo; j < jhi; ++j) acc += Sr[j] * Qr[j];
        }
    }
    out[gid] = acc;
}

extern "C" void kernel_launch(void* const* d_in, const int* in_sizes, int n_in,
                              void* d_out, int out_size, void* d_ws, size_t ws_size,
                              hipStream_t stream) {
    (void)in_sizes; (void)n_in; (void)out_size;
    const float* Q = (const float*)d_in[0];   // [16,256,32,32] f32
    const float* S = (const float*)d_in[1];   // [16,256,64,64] f32
    float* out = (float*)d_out;               // [16,1,65,65] f32

    const size_t QT_BYTES = (size_t)16 * 2 * 32 * 32 * 16 * 8 * 2;  //  8,388,608
    const size_t P_BYTES  = (size_t)16 * 64 * 32 * 80 * 4;          // 10,485,760

    if (ws_size < QT_BYTES + P_BYTES) {       // == 18,874,368, proven available
        naive_kernel<<<(67600 + 255) / 256, 256, 0, stream>>>(Q, S, out);
        return;
    }
    uint16_t* Qt = (uint16_t*)d_ws;
    float*    P  = (float*)((char*)d_ws + QT_BYTES);

    qtrans_kernel<<<dim3(32, 16), 256, 0, stream>>>(Q, Qt, P);
    corr_kernel<<<dim3(64, 2, 16), 256, 0, stream>>>(S, Qt, P);
    reduce_kernel<<<dim3(65, 16), 128, 0, stream>>>(P, out);
}